// Round 1
// baseline (336.645 us; speedup 1.0000x reference)
//
#include <hip/hip_runtime.h>
#include <hip/hip_bf16.h>
#include <cstdint>
#include <cstddef>

// LocalMSA fused v4: key-half split to halve LDS (64KB -> 32KB) and lift the
// 2-blocks/CU occupancy cap to 3 (launch_bounds(512,6) -> VGPR cap ~85).
// Softmax has no max-subtraction, so denominator (sm) and output (o) simply
// accumulate across the two key halves in registers; key order 0..255 is
// preserved -> arithmetic identical to v3 (absmax must stay ~0.0059).
// Per half: project K[128][64] + Vt[64][128] (16KB each, same swizzles as v3
// with halved row pitch for Vt), sync, attend all 256 q rows vs these 128
// keys, sync, overwrite with next half.
// Wave w owns q rows {16w+m_} and {128+16w+m_} (was 32w..32w+31).
// Sentinels: WRITE_SIZE must stay exactly 131072 KB (no spill);
// LDS_Block_Size 32768; VGPR <= 85.

typedef __attribute__((ext_vector_type(8))) short v8s;
typedef __attribute__((ext_vector_type(4))) float v4f;
typedef __attribute__((ext_vector_type(4))) unsigned short v4u;

#define MFMA16(a, b, c) __builtin_amdgcn_mfma_f32_16x16x32_bf16((a), (b), (c), 0, 0, 0)

constexpr int LL = 256;
constexpr int CC = 128;
constexpr int CH = 64;
constexpr int KS_BYTES = 128 * 128;   // K half  [128 l][64 cc-slot] bf16, 128B rows
constexpr int VT_BYTES = 64 * 256;    // Vt half [64 cc][128 l-slot] bf16, 256B rows

__device__ __forceinline__ unsigned short f2bf(float f) {
    union { __hip_bfloat16 b; unsigned short u; } cv;
    cv.b = __float2bfloat16(f);
    return cv.u;
}

__device__ __forceinline__ v8s load8_f32_bf16(const float* __restrict__ p) {
    float4 a = *reinterpret_cast<const float4*>(p);
    float4 b = *reinterpret_cast<const float4*>(p + 4);
    v8s r;
    r[0] = (short)f2bf(a.x); r[1] = (short)f2bf(a.y);
    r[2] = (short)f2bf(a.z); r[3] = (short)f2bf(a.w);
    r[4] = (short)f2bf(b.x); r[5] = (short)f2bf(b.y);
    r[6] = (short)f2bf(b.z); r[7] = (short)f2bf(b.w);
    return r;
}

__device__ __forceinline__ int swz128(int row, int byte_in_row) {
    return row * 128 + (byte_in_row ^ ((row & 7) << 4));
}
__device__ __forceinline__ int swz256(int row, int byte_in_row) {
    return row * 256 + (byte_in_row ^ ((row & 7) << 4));
}

// W fp32 -> bf16; Q rows (0..127) pre-scaled by 1/sqrt(128)
__global__ __launch_bounds__(256) void wconv_kernel(
    const float* __restrict__ W, unsigned short* __restrict__ Wb)
{
    int i = blockIdx.x * 256 + threadIdx.x;
    float4 v = reinterpret_cast<const float4*>(W)[i];
    const float s = (i < 4096) ? 0.08838834764831845f : 1.0f;
    v4u o;
    o[0] = f2bf(v.x * s); o[1] = f2bf(v.y * s); o[2] = f2bf(v.z * s); o[3] = f2bf(v.w * s);
    reinterpret_cast<v4u*>(Wb)[i] = o;
}

__global__ __launch_bounds__(512, 6) void lmsa_kernel(
    const float* __restrict__ x, const unsigned short* __restrict__ Wb,
    const float* __restrict__ bias, float* __restrict__ out)
{
    __shared__ char smem[KS_BYTES + VT_BYTES];   // 32 KB static
    char* KsB = smem;
    char* VtB = smem + KS_BYTES;

    const int bgh  = blockIdx.x;
    const int bg   = bgh >> 1;
    const int h    = bgh & 1;
    const int tid  = threadIdx.x;
    const int wave = tid >> 6;
    const int lane = tid & 63;
    const int m_   = lane & 15;
    const int g    = lane >> 4;
    const int pm   = 8 * (m_ >> 2) + (m_ & 3);   // within-32 slot base

    const float* xB = x + (size_t)bg * (LL * CC);
    const size_t obase0 = (size_t)bg * (LL * CC);

    const unsigned short* Wq = Wb + (0 * CC + h * CH) * CC;   // pre-scaled
    const unsigned short* Wk = Wb + (1 * CC + h * CH) * CC;
    const unsigned short* Wv = Wb + (2 * CC + h * CH) * CC;
    const float* bq = bias + 0 * CC + h * CH;
    const float* bk = bias + 1 * CC + h * CH;
    const float* bv = bias + 2 * CC + h * CH;

    const float qscale = 0.08838834764831845f;

    // K bias hoist (indexed by col = 16nt+m_)
    float bkr[4];
    #pragma unroll
    for (int nt = 0; nt < 4; ++nt) bkr[nt] = bk[16 * nt + m_];

    // x fragments: q-group 0 rows 16w+m_, q-group 1 rows 128+16w+m_
    v8s af0[4], af1[4];
    #pragma unroll
    for (int ks = 0; ks < 4; ++ks)
        af0[ks] = load8_f32_bf16(xB + (16 * wave + m_) * CC + 32 * ks + 8 * g);
    #pragma unroll
    for (int ks = 0; ks < 4; ++ks)
        af1[ks] = load8_f32_bf16(xB + (128 + 16 * wave + m_) * CC + 32 * ks + 8 * g);

    // ---- Q^T: D[cc][q]; row=cc=16mtc+4g+r, col=q=(128qg+16w)+m_ ----
    v8s qf[2][2];
    #pragma unroll
    for (int qg = 0; qg < 2; ++qg) {
        v4f qacc[4];
        #pragma unroll
        for (int mtc = 0; mtc < 4; ++mtc) {
            v4f acc = {0.f, 0.f, 0.f, 0.f};
            #pragma unroll
            for (int ks = 0; ks < 4; ++ks) {
                v8s wf = *reinterpret_cast<const v8s*>(Wq + (16 * mtc + m_) * CC + 32 * ks + 8 * g);
                acc = MFMA16(wf, qg ? af1[ks] : af0[ks], acc);
            }
            #pragma unroll
            for (int r = 0; r < 4; ++r)
                qacc[mtc][r] = acc[r] + bq[16 * mtc + 4 * g + r] * qscale;  // Wq pre-scaled
        }
        // pack B-frag: slot 8g+j <-> phys cc 32ks+16(j>>2)+4g+(j&3)
        #pragma unroll
        for (int ks = 0; ks < 2; ++ks)
            #pragma unroll
            for (int j = 0; j < 8; ++j)
                qf[qg][ks][j] = (short)f2bf(qacc[2 * ks + (j >> 2)][j & 3]);
    }

    // persistent accumulators across key halves
    v4f o[2][4];
    #pragma unroll
    for (int qg = 0; qg < 2; ++qg)
        #pragma unroll
        for (int nt = 0; nt < 4; ++nt) o[qg][nt] = v4f{0.f, 0.f, 0.f, 0.f};
    float sm[2] = {0.f, 0.f};

    #pragma unroll
    for (int hf = 0; hf < 2; ++hf) {
        // ---- K half: D[l][cc]; in-half row l = 16w+4g+r, phys cc permuted ----
        #pragma unroll 2
        for (int nt = 0; nt < 4; ++nt) {
            v8s bf[4];
            #pragma unroll
            for (int ks = 0; ks < 4; ++ks)
                bf[ks] = *reinterpret_cast<const v8s*>(Wk + (16 * nt + m_) * CC + 32 * ks + 8 * g);
            const int kcol = (32 * (nt >> 1) + 4 * (nt & 1) + pm) << 1;
            v4f acc = {0.f, 0.f, 0.f, 0.f};
            #pragma unroll
            for (int ks = 0; ks < 4; ++ks)
                acc = MFMA16(hf ? af1[ks] : af0[ks], bf[ks], acc);
            #pragma unroll
            for (int r = 0; r < 4; ++r)
                *(unsigned short*)(KsB + swz128(16 * wave + 4 * g + r, kcol)) =
                    f2bf(acc[r] + bkr[nt]);
        }

        // ---- Vt half: D[cc][l]; row=cc=16mtc+4g+r, in-half l group = wave ----
        {
            const int vcol = (32 * (wave >> 1) + 4 * (wave & 1) + pm) << 1;
            #pragma unroll 2
            for (int mtc = 0; mtc < 4; ++mtc) {
                v8s wf[4];
                #pragma unroll
                for (int ks = 0; ks < 4; ++ks)
                    wf[ks] = *reinterpret_cast<const v8s*>(Wv + (16 * mtc + m_) * CC + 32 * ks + 8 * g);
                v4f bvv = *reinterpret_cast<const v4f*>(bv + 16 * mtc + 4 * g);
                v4f acc = {0.f, 0.f, 0.f, 0.f};
                #pragma unroll
                for (int ks = 0; ks < 4; ++ks)
                    acc = MFMA16(wf[ks], hf ? af1[ks] : af0[ks], acc);
                #pragma unroll
                for (int r = 0; r < 4; ++r)
                    *(unsigned short*)(VtB + swz256(16 * mtc + 4 * g + r, vcol)) =
                        f2bf(acc[r] + bvv[r]);
            }
        }

        __syncthreads();

        // ---- attention vs this key half: keys 128hf + [0,128) ----
        #pragma unroll
        for (int qg = 0; qg < 2; ++qg) {
            #pragma unroll 2
            for (int c2 = 0; c2 < 4; ++c2) {       // 4 key-chunks of 32
                v4f s0 = {0.f, 0.f, 0.f, 0.f}, s1 = {0.f, 0.f, 0.f, 0.f};
                #pragma unroll
                for (int ks = 0; ks < 2; ++ks) {
                    v8s kf0 = *reinterpret_cast<const v8s*>(
                        KsB + swz128(32 * c2 + m_, (32 * ks + 8 * g) << 1));
                    s0 = MFMA16(kf0, qf[qg][ks], s0);
                }
                #pragma unroll
                for (int ks = 0; ks < 2; ++ks) {
                    v8s kf1 = *reinterpret_cast<const v8s*>(
                        KsB + swz128(32 * c2 + 16 + m_, (32 * ks + 8 * g) << 1));
                    s1 = MFMA16(kf1, qf[qg][ks], s1);
                }

                // lane(m_,g): P[q=m_][k=32c2+16t+4g+r]; A-frag slot 8g+j: t=j>>2, r=j&3
                v8s pf;
                #pragma unroll
                for (int j = 0; j < 4; ++j) {
                    float p = __expf(s0[j]); sm[qg] += p; pf[j] = (short)f2bf(p);
                }
                #pragma unroll
                for (int j = 0; j < 4; ++j) {
                    float p = __expf(s1[j]); sm[qg] += p; pf[4 + j] = (short)f2bf(p);
                }

                __builtin_amdgcn_s_setprio(1);
                #pragma unroll
                for (int nt = 0; nt < 4; ++nt) {
                    v8s vf = *reinterpret_cast<const v8s*>(
                        VtB + swz256(16 * nt + m_, 64 * c2 + 16 * g));
                    o[qg][nt] = MFMA16(pf, vf, o[qg][nt]);
                }
                __builtin_amdgcn_s_setprio(0);
            }
        }

        if (hf == 0) {
            // refresh af1 (L3-hot) so its live range doesn't span half-0
            // attention; issued before the barrier to hide latency under it
            #pragma unroll
            for (int ks = 0; ks < 4; ++ks)
                af1[ks] = load8_f32_bf16(xB + (128 + 16 * wave + m_) * CC + 32 * ks + 8 * g);
            __syncthreads();   // all reads of half-0 K/V done before overwrite
        }
    }

    // ------- normalize + store: q rows {128qg + 16w + 4g + r} -------
    #pragma unroll
    for (int qg = 0; qg < 2; ++qg) {
        float s = sm[qg];
        s += __shfl_xor(s, 16, 64);
        s += __shfl_xor(s, 32, 64);
        float inv[4];
        #pragma unroll
        for (int r = 0; r < 4; ++r) inv[r] = 1.0f / __shfl(s, 4 * g + r, 64);

        const int rowb = 128 * qg + 16 * wave;
        #pragma unroll
        for (int nt = 0; nt < 4; ++nt)
            #pragma unroll
            for (int r = 0; r < 4; ++r)
                out[obase0 + (size_t)(rowb + 4 * g + r) * CC + h * CH + 16 * nt + m_] =
                    o[qg][nt][r] * inv[r];
    }
}

extern "C" void kernel_launch(void* const* d_in, const int* in_sizes, int n_in,
                              void* d_out, int out_size, void* d_ws, size_t ws_size,
                              hipStream_t stream) {
    (void)in_sizes; (void)n_in; (void)ws_size; (void)out_size;
    const float* x = (const float*)d_in[0];
    const float* W = (const float*)d_in[1];
    const float* b = (const float*)d_in[2];
    float* out = (float*)d_out;
    unsigned short* Wb = (unsigned short*)d_ws;   // 96 KB bf16 W (Q rows pre-scaled)

    wconv_kernel<<<dim3(48), dim3(256), 0, stream>>>(W, Wb);
    lmsa_kernel<<<dim3(2048), dim3(512), 0, stream>>>(x, Wb, b, out);
}